// Round 4
// baseline (545.856 us; speedup 1.0000x reference)
//
#include <hip/hip_runtime.h>
#include <math.h>

#define B_  32
#define N_  256
#define D_  1024
#define H_  16
#define E_  512
#define ED_ 256
#define HD_ 64
#define QS_ 3072                  // merged qkv row stride
#define NEG_ (-3.4028234663852886e38f)

typedef __attribute__((ext_vector_type(8))) short short8;
typedef __attribute__((ext_vector_type(4))) float f32x4;
typedef __attribute__((ext_vector_type(16))) float f32x16;
typedef unsigned short ushort_t;
typedef unsigned int uint_t;

union U16x8 { uint4 u4; ushort_t s[8]; };

static __device__ __forceinline__ ushort_t f2bf(float f) {
    uint_t u = __builtin_bit_cast(uint_t, f);
    u = (u + 0x7fff + ((u >> 16) & 1)) >> 16;
    return (ushort_t)u;
}

// async global->LDS, 16 bytes per lane (m97 pattern)
static __device__ __forceinline__ void gload_lds16(const void* g, void* l) {
    __builtin_amdgcn_global_load_lds(
        (const __attribute__((address_space(1))) unsigned int*)g,
        (__attribute__((address_space(3))) unsigned int*)l, 16, 0, 0);
}

// ---------------- LayerNorm: fp32 in -> bf16 out -----------------------------
__global__ __launch_bounds__(256) void ln_bf16_kernel(const float* __restrict__ x,
                                                      const float* __restrict__ g,
                                                      const float* __restrict__ b,
                                                      ushort_t* __restrict__ out) {
    int row = blockIdx.x;
    const float* xr = x + (size_t)row * D_;
    ushort_t* yr = out + (size_t)row * D_;
    __shared__ float red[256];
    int t = threadIdx.x;
    float vals[4];
    float s = 0.f;
#pragma unroll
    for (int i = 0; i < 4; ++i) { vals[i] = xr[t + i * 256]; s += vals[i]; }
    red[t] = s; __syncthreads();
    for (int off = 128; off > 0; off >>= 1) { if (t < off) red[t] += red[t + off]; __syncthreads(); }
    float mean = red[0] * (1.f / D_);
    __syncthreads();
    float vs = 0.f;
#pragma unroll
    for (int i = 0; i < 4; ++i) { float d = vals[i] - mean; vs += d * d; }
    red[t] = vs; __syncthreads();
    for (int off = 128; off > 0; off >>= 1) { if (t < off) red[t] += red[t + off]; __syncthreads(); }
    float rstd = 1.f / sqrtf(red[0] * (1.f / D_) + 1e-5f);
#pragma unroll
    for (int i = 0; i < 4; ++i) {
        int c = t + i * 256;
        yr[c] = f2bf((vals[i] - mean) * rstd * g[c] + b[c]);
    }
}

// ---------------- fused prep: all weight transposes + concat bias ------------
// ids [0,4096): Wq/Wk/Wv/Wo (1024 32x32 tiles each)
// ids [4096,8192): W1 (K=1024,N=4096)   ids [8192,12288): W2 (K=4096,N=1024)
// ids [12288,12300): cbias 3072 elems
__global__ __launch_bounds__(256) void prep_kernel(
    const float* __restrict__ Wq, const float* __restrict__ Wk,
    const float* __restrict__ Wv, const float* __restrict__ Wo,
    const float* __restrict__ W1, const float* __restrict__ W2,
    const float* __restrict__ bq, const float* __restrict__ bk,
    const float* __restrict__ bv,
    ushort_t* __restrict__ qkvT, ushort_t* __restrict__ WoT,
    ushort_t* __restrict__ W1T, ushort_t* __restrict__ W2T,
    float* __restrict__ cb)
{
    int id = blockIdx.x;
    if (id >= 12288) {
        int i = (id - 12288) * 256 + threadIdx.x;
        cb[i] = (i < 1024) ? bq[i] : ((i < 2048) ? bk[i - 1024] : bv[i - 2048]);
        return;
    }
    const float* in; ushort_t* outp; int K, N, tid;
    if (id < 4096) {
        int wsel = id >> 10; tid = id & 1023; K = D_; N = D_;
        in   = (wsel == 0) ? Wq : (wsel == 1) ? Wk : (wsel == 2) ? Wv : Wo;
        outp = (wsel == 0) ? qkvT : (wsel == 1) ? qkvT + 1024 * 1024
             : (wsel == 2) ? qkvT + 2 * 1024 * 1024 : WoT;
    } else if (id < 8192) { tid = id - 4096; K = D_; N = 4 * D_; in = W1; outp = W1T; }
    else                  { tid = id - 8192; K = 4 * D_; N = D_; in = W2; outp = W2T; }
    int tilesX = N >> 5;
    int n0 = (tid % tilesX) * 32, k0 = (tid / tilesX) * 32;

    __shared__ float tile[32][33];
    int tx = threadIdx.x & 31, ty = threadIdx.x >> 5;   // ty 0..7
#pragma unroll
    for (int r = 0; r < 4; ++r)
        tile[ty + r * 8][tx] = in[(size_t)(k0 + ty + r * 8) * N + n0 + tx];
    __syncthreads();
#pragma unroll
    for (int r = 0; r < 4; ++r)
        outp[(size_t)(n0 + ty + r * 8) * K + k0 + tx] = f2bf(tile[tx][ty + r * 8]);
}

// ---------------- edge-bias projection: eb[b,e,h] ----------------------------
__global__ __launch_bounds__(256) void eb_kernel(const float* __restrict__ re,
                                                 const float* __restrict__ We,
                                                 const float* __restrict__ be,
                                                 float* __restrict__ eb) {
    __shared__ float rs[16 * 256];
    __shared__ float wl[256 * 16];
    int t = threadIdx.x;
    int be0 = blockIdx.x * 16;     // base (b*E+e)
#pragma unroll
    for (int i = 0; i < 16; ++i) wl[t + i * 256] = We[t + i * 256];
#pragma unroll
    for (int i = 0; i < 16; ++i) rs[t + i * 256] = re[(size_t)be0 * 256 + t + i * 256];
    __syncthreads();
    int el = t >> 4, h = t & 15;
    float s = be[h];
#pragma unroll 8
    for (int i = 0; i < 256; ++i) s += rs[el * 256 + i] * wl[i * 16 + h];
    eb[(size_t)(be0 + el) * 16 + h] = s;
}

// ---------------- edge scatter: last-writer-wins priority table --------------
// forward (src,dst) -> prio e ; reverse (dst,src) -> prio E+e (reverse scatter
// runs after forward in the reference, so any reverse beats any forward).
__global__ void scatter_kernel(const int* __restrict__ edges, const float* __restrict__ emask,
                               int* __restrict__ prio) {
    int idx = blockIdx.x * blockDim.x + threadIdx.x;   // b*E + e
    if (idx >= B_ * E_) return;
    if (emask[idx] == 0.f) return;
    int b = idx / E_, e = idx % E_;
    int s = edges[2 * idx], d = edges[2 * idx + 1];
    s = min(max(s, 0), N_ - 1);
    d = min(max(d, 0), N_ - 1);
    int* base = prio + (size_t)b * N_ * N_;
    atomicMax(&base[s * N_ + d], e);
    atomicMax(&base[d * N_ + s], e + E_);
}

// ---------------- bf16 MFMA GEMM (32x32x16): C = A[M,K] * BT[N,K]^T ---------
// 128x128 block, 4 waves in 2x2, each wave 64x64 = 2x2 tiles of 32x32.
// LDS XOR-swizzled on the global source side (R4: conflicts -> 0).
// R6: 1-D grid + XCD-chunked supertile decode (T1).
// R8: T4 counted-vmcnt pipeline. Per K-step: stage(next buf) -> vmcnt(4)
// (own CURRENT-buffer loads landed; next-tile's 4 stay in flight) -> raw
// s_barrier (all waves' cur loads landed) -> MFMA -> raw s_barrier (reads
// done, next iter may overwrite). Never drains vmcnt(0) in the main loop
// (m218: counted-vs-drain0 = +38-73%); __syncthreads would drain.
// sched_barrier(0) fences per rule #18; "memory" clobbers pin the
// global_load_lds intrinsics relative to the waitcnt.
// MODE 0: +bias -> bf16   1: +bias+res -> f32   2: silu(+bias) -> bf16
// MODE 3: +bias+res, *nm[row] -> f32
template<int MODE>
__global__ __launch_bounds__(256) void gemm_bf16(
    const ushort_t* __restrict__ A, const ushort_t* __restrict__ BT,
    const float* __restrict__ bias, const float* __restrict__ res,
    const float* __restrict__ nm, void* __restrict__ Cout,
    int M, int N, int K)
{
    __shared__ ushort_t As[2][128 * 32];   // 16 KB
    __shared__ ushort_t Bs[2][128 * 32];   // 16 KB
    int t = threadIdx.x;
    int lane = t & 63;
    int l31 = lane & 31, lh = lane >> 5;           // row/col in tile, k-half
    int w = t >> 6;
    int wr = (w >> 1) * 64, wc = (w & 1) * 64;

    // XCD-chunked supertile decode (bijective; hardware assigns bid -> XCD bid%8)
    int bid = blockIdx.x;
    int xcd = bid & 7;
    int lid = bid >> 3;            // sequential within this XCD's chunk
    int st  = lid >> 5;            // supertile = 8 rows x 4 cols = 32 blocks
    int ls  = lid & 31;
    int brow = xcd * 8 + (ls >> 2);
    int bcol = st * 4 + (ls & 3);
    int row0 = brow * 128, col0 = bcol * 128;

    const ushort_t* Ag = A + (size_t)row0 * K;
    const ushort_t* Bg = BT + (size_t)col0 * K;
    int r0 = t >> 2;                               // staging row 0..63
    int sl = t & 3;
    int sc = (sl ^ ((r0 >> 1) & 3)) * 8;           // swizzled source chunk

    f32x16 acc[2][2];
#pragma unroll
    for (int i = 0; i < 2; ++i)
#pragma unroll
        for (int j = 0; j < 2; ++j)
#pragma unroll
            for (int r = 0; r < 16; ++r) acc[i][j][r] = 0.f;

    auto stage = [&](int buf, int k0) {
        gload_lds16(Ag + (size_t)r0 * K + k0 + sc, (char*)As[buf] + t * 16);
        gload_lds16(Ag + (size_t)(64 + r0) * K + k0 + sc, (char*)As[buf] + 4096 + t * 16);
        gload_lds16(Bg + (size_t)r0 * K + k0 + sc, (char*)Bs[buf] + t * 16);
        gload_lds16(Bg + (size_t)(64 + r0) * K + k0 + sc, (char*)Bs[buf] + 4096 + t * 16);
    };

    stage(0, 0);                   // 4 loads in flight for buf0
    int cur = 0;

    for (int k0 = 0; k0 < K; k0 += 32) {
        if (k0 + 32 < K) {
            stage(cur ^ 1, k0 + 32);                       // +4 loads (next tile)
            asm volatile("s_waitcnt vmcnt(4)" ::: "memory"); // cur's 4 landed
        } else {
            asm volatile("s_waitcnt vmcnt(0)" ::: "memory"); // last tile: drain
        }
        __builtin_amdgcn_s_barrier();          // all waves: cur buffer ready
        __builtin_amdgcn_sched_barrier(0);     // don't hoist ds_read above

        const ushort_t* Ab = As[cur];
        const ushort_t* Bb = Bs[cur];
#pragma unroll
        for (int ks = 0; ks < 2; ++ks) {
            short8 af[2], bf[2];
#pragma unroll
            for (int it = 0; it < 2; ++it) {
                int m = wr + it * 32 + l31;
                int x = ((ks * 2 + lh) ^ ((m >> 1) & 3)) * 8;
                af[it] = *(const short8*)(const void*)(Ab + m * 32 + x);
            }
#pragma unroll
            for (int jt = 0; jt < 2; ++jt) {
                int n = wc + jt * 32 + l31;
                int x = ((ks * 2 + lh) ^ ((n >> 1) & 3)) * 8;
                bf[jt] = *(const short8*)(const void*)(Bb + n * 32 + x);
            }
#pragma unroll
            for (int it = 0; it < 2; ++it)
#pragma unroll
                for (int jt = 0; jt < 2; ++jt)
                    acc[it][jt] = __builtin_amdgcn_mfma_f32_32x32x16_bf16(af[it], bf[jt], acc[it][jt], 0, 0, 0);
        }
        __builtin_amdgcn_sched_barrier(0);     // don't sink ds_read below
        __builtin_amdgcn_s_barrier();          // reads of cur done everywhere
        cur ^= 1;
    }

    // C/D layout (m74/m101): col = lane&31, row = (reg&3) + 8*(reg>>2) + 4*(lane>>5)
#pragma unroll
    for (int it = 0; it < 2; ++it) {
#pragma unroll
        for (int jt = 0; jt < 2; ++jt) {
            int col = col0 + wc + jt * 32 + l31;
            float bcol_b = bias[col];
#pragma unroll
            for (int reg = 0; reg < 16; ++reg) {
                int row = row0 + wr + it * 32 + (reg & 3) + 8 * (reg >> 2) + 4 * lh;
                float v = acc[it][jt][reg] + bcol_b;
                if (MODE == 0) {
                    ((ushort_t*)Cout)[(size_t)row * N + col] = f2bf(v);
                } else if (MODE == 1) {
                    ((float*)Cout)[(size_t)row * N + col] = v + res[(size_t)row * N + col];
                } else if (MODE == 2) {
                    v = v / (1.f + __expf(-v));
                    ((ushort_t*)Cout)[(size_t)row * N + col] = f2bf(v);
                } else { // 3
                    v = (v + res[(size_t)row * N + col]) * nm[row];
                    ((float*)Cout)[(size_t)row * N + col] = v;
                }
            }
        }
    }
}

// ---------------- MFMA attention: block = (b, h, q-tile of 64) ---------------
// q/k/v live in one merged buffer with row stride QS_ (q:+0, k:+1024, v:+2048).
// R5: prio/eb/nm prefetched pre-barrier into regs (badd = fully folded additive
// bias, masked = -3e38); Q frags direct from global (Qs dropped); XCD-clustered
// block decode (h fastest) so the 16 heads sharing a prio slab + the 4 q-tiles
// sharing K/V hit one XCD's L2; setprio around MFMA clusters (T5, m191).
__global__ __launch_bounds__(256, 2) void attn_mfma_kernel(
    const ushort_t* __restrict__ qkv, const int* __restrict__ prio,
    const float* __restrict__ eb, const float* __restrict__ nm,
    ushort_t* __restrict__ out)
{
    // bijective XCD swizzle (grid 2048 % 8 == 0): logical ids 0..255 -> XCD 0, etc.
    int xb = blockIdx.x;
    int bid = (xb & 7) * 256 + (xb >> 3);
    int h = bid & 15, qt = (bid >> 4) & 3, b = bid >> 6;
    int t = threadIdx.x;

    __shared__ ushort_t Ks[256 * 72];    // 36864 B (reused as Ps[64*264])
    __shared__ ushort_t Vt[64 * 264];    // 33792 B  (transposed V: [d][key])

    int lane = t & 63, c = lane & 15, quad = lane >> 4;
    int w = t >> 6;
    int qbase = qt * 64 + w * 16 + quad * 4;   // +r, within-batch node index

    // ---- prio prefetch FIRST (longest dependent chain: prio -> eb) ----------
    int pr[16][4];
    const int* prp = prio + ((size_t)(b * N_ + qbase)) * N_ + c;
#pragma unroll
    for (int j = 0; j < 16; ++j)
#pragma unroll
        for (int r = 0; r < 4; ++r)
            pr[j][r] = prp[(size_t)r * N_ + j * 16];

    float nmq[4];
#pragma unroll
    for (int r = 0; r < 4; ++r) nmq[r] = nm[b * N_ + qbase + r];
    float nmk[16];
#pragma unroll
    for (int j = 0; j < 16; ++j) nmk[j] = nm[b * N_ + j * 16 + c];

    // ---- Q fragments direct from global (16B aligned, L2-resident) ----------
    const ushort_t* qg = qkv + ((size_t)(b * N_ + qt * 64 + w * 16 + c)) * QS_ + h * HD_;
    short8 aq0 = *(const short8*)(const void*)(qg + quad * 8);
    short8 aq1 = *(const short8*)(const void*)(qg + 32 + quad * 8);

    // ---- K / V staging ----
    int lr = t >> 3, lc = (t & 7) * 8;
    const ushort_t* kg = qkv + ((size_t)(b * N_)) * QS_ + 1024 + h * HD_;
#pragma unroll
    for (int r = 0; r < 256; r += 32)
        *(uint4*)&Ks[(lr + r) * 72 + lc] = *(const uint4*)&kg[(size_t)(lr + r) * QS_ + lc];
    const ushort_t* vg = qkv + ((size_t)(b * N_)) * QS_ + 2048 + h * HD_;
#pragma unroll
    for (int r = 0; r < 256; r += 32) {
        U16x8 uu; uu.u4 = *(const uint4*)&vg[(size_t)(lr + r) * QS_ + lc];
#pragma unroll
        for (int i = 0; i < 8; ++i)
            Vt[(lc + i) * 264 + lr + r] = uu.s[i];
    }

    // ---- additive bias precompute: badd = ok ? eb : -3e38 (mask folded) -----
    // -3e38 absorbs |score|<=~16 without overflow; exp(x-m) -> 0 when any
    // unmasked entry exists. All-masked rows only occur for nmq==0 rows, which
    // the final *node_masks zeroes (matches reference up to that dead output).
    const float* ebb = eb + (size_t)b * E_ * H_ + h;
    float badd[16][4];
#pragma unroll
    for (int j = 0; j < 16; ++j) {
        int key = j * 16 + c;
#pragma unroll
        for (int r = 0; r < 4; ++r) {
            int p = pr[j][r];
            float bias = 0.f;
            bool adj = (key == qbase + r);
            if (p >= 0) {
                int e = (p >= E_) ? p - E_ : p;
                bias = ebb[(size_t)e * H_];
                adj = true;
            }
            bool ok = adj && (nmq[r] != 0.f) && (nmk[j] != 0.f);
            badd[j][r] = ok ? bias : -3.0e38f;
        }
    }
    __syncthreads();

    // ---- QK^T ----
    f32x4 z = {0.f, 0.f, 0.f, 0.f};
    f32x4 acc[16];
#pragma unroll
    for (int j = 0; j < 16; ++j) acc[j] = z;
    __builtin_amdgcn_s_setprio(1);
#pragma unroll
    for (int j = 0; j < 16; ++j) {
        short8 b0 = *(const short8*)(const void*)(Ks + (j * 16 + c) * 72 + quad * 8);
        short8 b1 = *(const short8*)(const void*)(Ks + (j * 16 + c) * 72 + 32 + quad * 8);
        acc[j] = __builtin_amdgcn_mfma_f32_16x16x32_bf16(aq0, b0, acc[j], 0, 0, 0);
        acc[j] = __builtin_amdgcn_mfma_f32_16x16x32_bf16(aq1, b1, acc[j], 0, 0, 0);
    }
    __builtin_amdgcn_s_setprio(0);

    // ---- scale + folded bias/mask (pure FMA, no loads on critical path) -----
#pragma unroll
    for (int j = 0; j < 16; ++j)
#pragma unroll
        for (int r = 0; r < 4; ++r)
            acc[j][r] = acc[j][r] * 0.125f + badd[j][r];

    // ---- softmax per row (16 lanes of a quad hold one row across 16 tiles) --
    float inv[4];
#pragma unroll
    for (int r = 0; r < 4; ++r) {
        float m = acc[0][r];
#pragma unroll
        for (int j = 1; j < 16; ++j) m = fmaxf(m, acc[j][r]);
        m = fmaxf(m, __shfl_xor(m, 1));
        m = fmaxf(m, __shfl_xor(m, 2));
        m = fmaxf(m, __shfl_xor(m, 4));
        m = fmaxf(m, __shfl_xor(m, 8));
        float s = 0.f;
#pragma unroll
        for (int j = 0; j < 16; ++j) {
            float p = __expf(acc[j][r] - m);
            acc[j][r] = p;
            s += p;
        }
        s += __shfl_xor(s, 1);
        s += __shfl_xor(s, 2);
        s += __shfl_xor(s, 4);
        s += __shfl_xor(s, 8);
        inv[r] = 1.f / s;
    }

    __syncthreads();            // everyone done reading Ks
    ushort_t* Ps = Ks;          // reuse as P [64][264]
#pragma unroll
    for (int j = 0; j < 16; ++j)
#pragma unroll
        for (int r = 0; r < 4; ++r)
            Ps[(w * 16 + quad * 4 + r) * 264 + j * 16 + c] = f2bf(acc[j][r] * inv[r]);
    // wave-local RAW only: each wave reads exactly the P rows it wrote
    asm volatile("s_waitcnt lgkmcnt(0)" ::: "memory");

    // ---- PV ----
    f32x4 oc[4];
#pragma unroll
    for (int dt = 0; dt < 4; ++dt) oc[dt] = z;
    __builtin_amdgcn_s_setprio(1);
#pragma unroll
    for (int k0 = 0; k0 < 256; k0 += 32) {
        short8 ap = *(const short8*)(const void*)(Ps + (w * 16 + c) * 264 + k0 + quad * 8);
#pragma unroll
        for (int dt = 0; dt < 4; ++dt) {
            short8 bv = *(const short8*)(const void*)(Vt + (dt * 16 + c) * 264 + k0 + quad * 8);
            oc[dt] = __builtin_amdgcn_mfma_f32_16x16x32_bf16(ap, bv, oc[dt], 0, 0, 0);
        }
    }
    __builtin_amdgcn_s_setprio(0);
    ushort_t* og = out + ((size_t)(b * N_ + qt * 64 + w * 16)) * D_ + h * HD_;
#pragma unroll
    for (int dt = 0; dt < 4; ++dt)
#pragma unroll
        for (int r = 0; r < 4; ++r)
            og[(size_t)(quad * 4 + r) * D_ + dt * 16 + c] = f2bf(oc[dt][r]);
}

extern "C" void kernel_launch(void* const* d_in, const int* in_sizes, int n_in,
                              void* d_out, int out_size, void* d_ws, size_t ws_size,
                              hipStream_t stream) {
    const float* x     = (const float*)d_in[0];
    const float* nm    = (const float*)d_in[1];
    const int*   edges = (const int*)d_in[2];
    const float* emask = (const float*)d_in[3];
    const float* remb  = (const float*)d_in[4];
    const float* ln_g  = (const float*)d_in[5];
    const float* ln_b  = (const float*)d_in[6];
    const float* Wq = (const float*)d_in[7];  const float* bq = (const float*)d_in[8];
    const float* Wk = (const float*)d_in[9];  const float* bk = (const float*)d_in[10];
    const float* Wv = (const float*)d_in[11]; const float* bv = (const float*)d_in[12];
    const float* We = (const float*)d_in[13]; const float* be = (const float*)d_in[14];
    const float* Wo = (const float*)d_in[15]; const float* bo = (const float*)d_in[16];
    const float* ff_g = (const float*)d_in[17]; const float* ff_b = (const float*)d_in[18];
    const float* W1 = (const float*)d_in[19]; const float* b1 = (const float*)d_in[20];
    const float* W2 = (const float*)d_in[21]; const float* b2 = (const float*)d_in[22];
    float* out = (float*)d_out;

    char* ws = (char*)d_ws;
    const size_t MB = 1ll << 20;
    int*      prio = (int*)ws;                       // 0..8 MB
    float*    ebuf = (float*)(ws + 8 * MB);          // 8..9 MB
    ushort_t* xn   = (ushort_t*)(ws + 9 * MB);       // 9..25 MB (reused: attn_out)
    float*    x2   = (float*)(ws + 25 * MB);         // 25..57 MB
    ushort_t* hn   = (ushort_t*)(ws + 57 * MB);      // 57..73 MB
    ushort_t* qkv  = (ushort_t*)(ws + 73 * MB);      // 73..121 MB [8192][3072]
    ushort_t* mid  = qkv;                            // 73..137 MB (qkv dead by then)
    ushort_t* qkvT = (ushort_t*)(ws + 137 * MB);     // 137..143 MB [3072][1024]
    ushort_t* WoT  = (ushort_t*)(ws + 143 * MB);     // 143..145 MB
    ushort_t* W1T  = (ushort_t*)(ws + 145 * MB);     // 145..153 MB [4096][1024]
    ushort_t* W2T  = (ushort_t*)(ws + 153 * MB);     // 153..161 MB [1024][4096]
    float*    cb   = (float*)(ws + 161 * MB);        // 161..161.02 MB [3072]
    ushort_t* aout = xn;

    const int M = B_ * N_;   // 8192

    (void)hipMemsetAsync(prio, 0xFF, (size_t)B_ * N_ * N_ * sizeof(int), stream);
    eb_kernel<<<B_ * E_ / 16, 256, 0, stream>>>(remb, We, be, ebuf);
    scatter_kernel<<<(B_ * E_ + 255) / 256, 256, 0, stream>>>(edges, emask, prio);

    prep_kernel<<<12300, 256, 0, stream>>>(Wq, Wk, Wv, Wo, W1, W2, bq, bk, bv,
                                           qkvT, WoT, W1T, W2T, cb);

    ln_bf16_kernel<<<M, 256, 0, stream>>>(x, ln_g, ln_b, xn);

    // 1-D grids: nbx*64 blocks (nbx = N/128)
    gemm_bf16<0><<<24 * 64, 256, 0, stream>>>(xn, qkvT, cb, nullptr, nullptr, qkv, M, QS_, D_);

    attn_mfma_kernel<<<B_ * H_ * 4, 256, 0, stream>>>(qkv, prio, ebuf, nm, aout);

    gemm_bf16<1><<<8 * 64, 256, 0, stream>>>(aout, WoT, bo, x, nullptr, x2, M, D_, D_);
    ln_bf16_kernel<<<M, 256, 0, stream>>>(x2, ff_g, ff_b, hn);

    gemm_bf16<2><<<32 * 64, 256, 0, stream>>>(hn, W1T, b1, nullptr, nullptr, mid, M, 4 * D_, D_);
    gemm_bf16<3><<<8 * 64, 256, 0, stream>>>(mid, W2T, b2, x2, nm, out, M, D_, 4 * D_);
}

// Round 5
// 536.380 us; speedup vs baseline: 1.0177x; 1.0177x over previous
//
#include <hip/hip_runtime.h>
#include <math.h>

#define B_  32
#define N_  256
#define D_  1024
#define H_  16
#define E_  512
#define ED_ 256
#define HD_ 64
#define QS_ 3072                  // merged qkv row stride
#define NEG_ (-3.4028234663852886e38f)

typedef __attribute__((ext_vector_type(8))) short short8;
typedef __attribute__((ext_vector_type(4))) float f32x4;
typedef __attribute__((ext_vector_type(16))) float f32x16;
typedef unsigned short ushort_t;
typedef unsigned int uint_t;

union U16x8 { uint4 u4; ushort_t s[8]; };

static __device__ __forceinline__ ushort_t f2bf(float f) {
    uint_t u = __builtin_bit_cast(uint_t, f);
    u = (u + 0x7fff + ((u >> 16) & 1)) >> 16;
    return (ushort_t)u;
}

// async global->LDS, 16 bytes per lane (m97 pattern)
static __device__ __forceinline__ void gload_lds16(const void* g, void* l) {
    __builtin_amdgcn_global_load_lds(
        (const __attribute__((address_space(1))) unsigned int*)g,
        (__attribute__((address_space(3))) unsigned int*)l, 16, 0, 0);
}

// ---------------- LayerNorm: fp32 in -> bf16 out -----------------------------
__global__ __launch_bounds__(256) void ln_bf16_kernel(const float* __restrict__ x,
                                                      const float* __restrict__ g,
                                                      const float* __restrict__ b,
                                                      ushort_t* __restrict__ out) {
    int row = blockIdx.x;
    const float* xr = x + (size_t)row * D_;
    ushort_t* yr = out + (size_t)row * D_;
    __shared__ float red[256];
    int t = threadIdx.x;
    float vals[4];
    float s = 0.f;
#pragma unroll
    for (int i = 0; i < 4; ++i) { vals[i] = xr[t + i * 256]; s += vals[i]; }
    red[t] = s; __syncthreads();
    for (int off = 128; off > 0; off >>= 1) { if (t < off) red[t] += red[t + off]; __syncthreads(); }
    float mean = red[0] * (1.f / D_);
    __syncthreads();
    float vs = 0.f;
#pragma unroll
    for (int i = 0; i < 4; ++i) { float d = vals[i] - mean; vs += d * d; }
    red[t] = vs; __syncthreads();
    for (int off = 128; off > 0; off >>= 1) { if (t < off) red[t] += red[t + off]; __syncthreads(); }
    float rstd = 1.f / sqrtf(red[0] * (1.f / D_) + 1e-5f);
#pragma unroll
    for (int i = 0; i < 4; ++i) {
        int c = t + i * 256;
        yr[c] = f2bf((vals[i] - mean) * rstd * g[c] + b[c]);
    }
}

// ---------------- fused prep: all weight transposes + concat bias ------------
__global__ __launch_bounds__(256) void prep_kernel(
    const float* __restrict__ Wq, const float* __restrict__ Wk,
    const float* __restrict__ Wv, const float* __restrict__ Wo,
    const float* __restrict__ W1, const float* __restrict__ W2,
    const float* __restrict__ bq, const float* __restrict__ bk,
    const float* __restrict__ bv,
    ushort_t* __restrict__ qkvT, ushort_t* __restrict__ WoT,
    ushort_t* __restrict__ W1T, ushort_t* __restrict__ W2T,
    float* __restrict__ cb)
{
    int id = blockIdx.x;
    if (id >= 12288) {
        int i = (id - 12288) * 256 + threadIdx.x;
        cb[i] = (i < 1024) ? bq[i] : ((i < 2048) ? bk[i - 1024] : bv[i - 2048]);
        return;
    }
    const float* in; ushort_t* outp; int K, N, tid;
    if (id < 4096) {
        int wsel = id >> 10; tid = id & 1023; K = D_; N = D_;
        in   = (wsel == 0) ? Wq : (wsel == 1) ? Wk : (wsel == 2) ? Wv : Wo;
        outp = (wsel == 0) ? qkvT : (wsel == 1) ? qkvT + 1024 * 1024
             : (wsel == 2) ? qkvT + 2 * 1024 * 1024 : WoT;
    } else if (id < 8192) { tid = id - 4096; K = D_; N = 4 * D_; in = W1; outp = W1T; }
    else                  { tid = id - 8192; K = 4 * D_; N = D_; in = W2; outp = W2T; }
    int tilesX = N >> 5;
    int n0 = (tid % tilesX) * 32, k0 = (tid / tilesX) * 32;

    __shared__ float tile[32][33];
    int tx = threadIdx.x & 31, ty = threadIdx.x >> 5;   // ty 0..7
#pragma unroll
    for (int r = 0; r < 4; ++r)
        tile[ty + r * 8][tx] = in[(size_t)(k0 + ty + r * 8) * N + n0 + tx];
    __syncthreads();
#pragma unroll
    for (int r = 0; r < 4; ++r)
        outp[(size_t)(n0 + ty + r * 8) * K + k0 + tx] = f2bf(tile[tx][ty + r * 8]);
}

// ---------------- edge-bias projection: eb[b,e,h] ----------------------------
__global__ __launch_bounds__(256) void eb_kernel(const float* __restrict__ re,
                                                 const float* __restrict__ We,
                                                 const float* __restrict__ be,
                                                 float* __restrict__ eb) {
    __shared__ float rs[16 * 256];
    __shared__ float wl[256 * 16];
    int t = threadIdx.x;
    int be0 = blockIdx.x * 16;     // base (b*E+e)
#pragma unroll
    for (int i = 0; i < 16; ++i) wl[t + i * 256] = We[t + i * 256];
#pragma unroll
    for (int i = 0; i < 16; ++i) rs[t + i * 256] = re[(size_t)be0 * 256 + t + i * 256];
    __syncthreads();
    int el = t >> 4, h = t & 15;
    float s = be[h];
#pragma unroll 8
    for (int i = 0; i < 256; ++i) s += rs[el * 256 + i] * wl[i * 16 + h];
    eb[(size_t)(be0 + el) * 16 + h] = s;
}

// ---------------- edge scatter: last-writer-wins priority table --------------
__global__ void scatter_kernel(const int* __restrict__ edges, const float* __restrict__ emask,
                               int* __restrict__ prio) {
    int idx = blockIdx.x * blockDim.x + threadIdx.x;   // b*E + e
    if (idx >= B_ * E_) return;
    if (emask[idx] == 0.f) return;
    int b = idx / E_, e = idx % E_;
    int s = edges[2 * idx], d = edges[2 * idx + 1];
    s = min(max(s, 0), N_ - 1);
    d = min(max(d, 0), N_ - 1);
    int* base = prio + (size_t)b * N_ * N_;
    atomicMax(&base[s * N_ + d], e);
    atomicMax(&base[d * N_ + s], e + E_);
}

// ---------------- bf16 MFMA GEMM 128x128 (R1 structure, reverted) ------------
// Single-buffered, 2 __syncthreads per K-step — measured best for the small-
// grid shapes (modes 1,3). R6 XCD supertile decode retained.
// MODE 1: +bias+res -> f32    MODE 3: +bias+res, *nm[row] -> f32
template<int MODE>
__global__ __launch_bounds__(256) void gemm_bf16(
    const ushort_t* __restrict__ A, const ushort_t* __restrict__ BT,
    const float* __restrict__ bias, const float* __restrict__ res,
    const float* __restrict__ nm, void* __restrict__ Cout,
    int M, int N, int K)
{
    __shared__ ushort_t As[128 * 32];
    __shared__ ushort_t Bs[128 * 32];
    int t = threadIdx.x;
    int lane = t & 63;
    int l31 = lane & 31, lh = lane >> 5;
    int w = t >> 6;
    int wr = (w >> 1) * 64, wc = (w & 1) * 64;

    int bid = blockIdx.x;
    int xcd = bid & 7;
    int lid = bid >> 3;
    int st  = lid >> 5;
    int ls  = lid & 31;
    int brow = xcd * 8 + (ls >> 2);
    int bcol = st * 4 + (ls & 3);
    int row0 = brow * 128, col0 = bcol * 128;

    const ushort_t* Ag = A + (size_t)row0 * K;
    const ushort_t* Bg = BT + (size_t)col0 * K;
    int r0 = t >> 2;
    int sl = t & 3;
    int sc = (sl ^ ((r0 >> 1) & 3)) * 8;

    f32x16 acc[2][2];
#pragma unroll
    for (int i = 0; i < 2; ++i)
#pragma unroll
        for (int j = 0; j < 2; ++j)
#pragma unroll
            for (int r = 0; r < 16; ++r) acc[i][j][r] = 0.f;

    for (int k0 = 0; k0 < K; k0 += 32) {
        gload_lds16(Ag + (size_t)r0 * K + k0 + sc, (char*)As + t * 16);
        gload_lds16(Ag + (size_t)(64 + r0) * K + k0 + sc, (char*)As + 4096 + t * 16);
        gload_lds16(Bg + (size_t)r0 * K + k0 + sc, (char*)Bs + t * 16);
        gload_lds16(Bg + (size_t)(64 + r0) * K + k0 + sc, (char*)Bs + 4096 + t * 16);
        __syncthreads();
#pragma unroll
        for (int ks = 0; ks < 2; ++ks) {
            short8 af[2], bf[2];
#pragma unroll
            for (int it = 0; it < 2; ++it) {
                int m = wr + it * 32 + l31;
                int x = ((ks * 2 + lh) ^ ((m >> 1) & 3)) * 8;
                af[it] = *(const short8*)(const void*)(As + m * 32 + x);
            }
#pragma unroll
            for (int jt = 0; jt < 2; ++jt) {
                int n = wc + jt * 32 + l31;
                int x = ((ks * 2 + lh) ^ ((n >> 1) & 3)) * 8;
                bf[jt] = *(const short8*)(const void*)(Bs + n * 32 + x);
            }
#pragma unroll
            for (int it = 0; it < 2; ++it)
#pragma unroll
                for (int jt = 0; jt < 2; ++jt)
                    acc[it][jt] = __builtin_amdgcn_mfma_f32_32x32x16_bf16(af[it], bf[jt], acc[it][jt], 0, 0, 0);
        }
        __syncthreads();
    }

#pragma unroll
    for (int it = 0; it < 2; ++it) {
#pragma unroll
        for (int jt = 0; jt < 2; ++jt) {
            int col = col0 + wc + jt * 32 + l31;
            float bcol_b = bias[col];
#pragma unroll
            for (int reg = 0; reg < 16; ++reg) {
                int row = row0 + wr + it * 32 + (reg & 3) + 8 * (reg >> 2) + 4 * lh;
                float v = acc[it][jt][reg] + bcol_b;
                if (MODE == 1) {
                    ((float*)Cout)[(size_t)row * N + col] = v + res[(size_t)row * N + col];
                } else { // 3
                    v = (v + res[(size_t)row * N + col]) * nm[row];
                    ((float*)Cout)[(size_t)row * N + col] = v;
                }
            }
        }
    }
}

// ---------------- 256x256 8-phase bf16 GEMM (T1+T2+T3+T4+T5) ----------------
// BM=BN=256, BK=64, 512 threads = 8 waves (2M x 4N), wave output 128x64.
// LDS 128 KB: [2 dbuf][2 half][128 rows][64 k] for A and B, XOR-swizzled
// (slot = chunk ^ (row&7); inverse applied on the global source address so
// global_load_lds writes linearly — guide rule #21).
// Schedule: phase G (0..7 per 2-K-tile iteration) stages half (G&3) of tile
// (G>>2)+1 into the OTHER buffer (never the one being read; writes to the
// buffer of tile tau+2 only begin after tau's last read barrier). vmcnt is
// counted (2 = just-issued half) at tile-entry phases only, never drained
// mid-loop (T4). setprio around the MFMA cluster (T5).
// MODE 0: +bias -> bf16    MODE 2: silu(+bias) -> bf16
// Requires M==8192 (32 brows = 8 XCD x 4), N = NBN*256, K % 128 == 0.
template<int MODE, int NBN>
__global__ __launch_bounds__(512) void gemm256(
    const ushort_t* __restrict__ A, const ushort_t* __restrict__ BT,
    const float* __restrict__ bias, void* __restrict__ Cout,
    int M, int N, int K)
{
    __shared__ ushort_t Asm_[2][2][128 * 64];   // 64 KB
    __shared__ ushort_t Bsm_[2][2][128 * 64];   // 64 KB

    int t = threadIdx.x;
    int lane = t & 63;
    int w = t >> 6;                 // 0..7
    int wm = w >> 2, wn = w & 3;    // 2M x 4N wave grid
    int c2 = lane & 15, quad = lane >> 4;

    // XCD-chunked decode: XCD x owns brows [x*4, x*4+4), bcol fastest
    int bid = blockIdx.x;
    int xcd = bid & 7, lid = bid >> 3;
    int brow = xcd * 4 + lid / NBN;
    int bcol = lid % NBN;
    int row0 = brow * 256, col0 = bcol * 256;

    const ushort_t* Ag = A + (size_t)row0 * K;
    const ushort_t* Bg = BT + (size_t)col0 * K;

    // staging: thread t covers linear LDS bytes [t*16) in each 8KB call;
    // row = call*64 + t>>3, slot = t&7, source chunk = slot ^ (row&7)
    int srow = t >> 3, slot = t & 7;
    int schunk8 = (slot ^ (srow & 7)) * 8;      // elems

    auto stage_half = [&](int bf, int hh, int kt) {
        const ushort_t* g = (hh < 2) ? Ag : Bg;
        int h = hh & 1;
        char* l = (hh < 2) ? (char*)&Asm_[bf][h][0] : (char*)&Bsm_[bf][h][0];
        gload_lds16(g + (size_t)(h * 128 + srow) * K + kt * 64 + schunk8, l + t * 16);
        gload_lds16(g + (size_t)(h * 128 + 64 + srow) * K + kt * 64 + schunk8, l + 8192 + t * 16);
    };

    // read-side swizzled chunk byte offset (row&7 == c2&7 for all our rows)
    int choff[2];
    choff[0] = ((0 * 4 + quad) ^ (c2 & 7)) * 16;
    choff[1] = ((1 * 4 + quad) ^ (c2 & 7)) * 16;
    const int bhalf = wn >> 1;
    const int bco = (wn & 1) * 64;

    f32x4 acc[8][4];
#pragma unroll
    for (int a_ = 0; a_ < 8; ++a_)
#pragma unroll
        for (int b_ = 0; b_ < 4; ++b_)
#pragma unroll
            for (int r = 0; r < 4; ++r) acc[a_][b_][r] = 0.f;

    // prologue: all 4 halves of tile 0 -> buf 0
    stage_half(0, 0, 0); stage_half(0, 1, 0); stage_half(0, 2, 0); stage_half(0, 3, 0);

    int T = K >> 6;                 // K-tiles (even)
    for (int i = 0; i < (T >> 1); ++i) {
#pragma unroll
        for (int hf = 0; hf < 2; ++hf) {
            int tau = 2 * i + hf;
            int bufc = tau & 1;
            short8 bfr[4][2];
#pragma unroll
            for (int q = 0; q < 4; ++q) {
                if (tau + 1 < T) stage_half((tau + 1) & 1, q, tau + 1);
                if (q == 0) {
                    if (tau + 1 < T) asm volatile("s_waitcnt vmcnt(2)" ::: "memory");
                    else             asm volatile("s_waitcnt vmcnt(0)" ::: "memory");
                }
                __builtin_amdgcn_s_barrier();
                __builtin_amdgcn_sched_barrier(0);
                if (q == 0) {       // B fragments for this tile (reused q=0..3)
#pragma unroll
                    for (int jt = 0; jt < 4; ++jt)
#pragma unroll
                        for (int ks = 0; ks < 2; ++ks)
                            bfr[jt][ks] = *(const short8*)((const char*)&Bsm_[bufc][bhalf][0]
                                           + (bco + jt * 16 + c2) * 128 + choff[ks]);
                }
                short8 afr[2][2];
#pragma unroll
                for (int it = 0; it < 2; ++it)
#pragma unroll
                    for (int ks = 0; ks < 2; ++ks)
                        afr[it][ks] = *(const short8*)((const char*)&Asm_[bufc][wm][0]
                                       + (q * 32 + it * 16 + c2) * 128 + choff[ks]);
                asm volatile("s_waitcnt lgkmcnt(0)" ::: "memory");
                __builtin_amdgcn_sched_barrier(0);
                __builtin_amdgcn_s_setprio(1);
#pragma unroll
                for (int it = 0; it < 2; ++it)
#pragma unroll
                    for (int jt = 0; jt < 4; ++jt) {
                        acc[q * 2 + it][jt] = __builtin_amdgcn_mfma_f32_16x16x32_bf16(
                            afr[it][0], bfr[jt][0], acc[q * 2 + it][jt], 0, 0, 0);
                        acc[q * 2 + it][jt] = __builtin_amdgcn_mfma_f32_16x16x32_bf16(
                            afr[it][1], bfr[jt][1], acc[q * 2 + it][jt], 0, 0, 0);
                    }
                __builtin_amdgcn_s_setprio(0);
                __builtin_amdgcn_sched_barrier(0);
                __builtin_amdgcn_s_barrier();
            }
        }
    }

    // epilogue: 16x16 C/D layout (m89): row = quad*4 + r, col = c2
#pragma unroll
    for (int q = 0; q < 4; ++q)
#pragma unroll
        for (int it = 0; it < 2; ++it) {
            int row = row0 + wm * 128 + q * 32 + it * 16 + quad * 4;
#pragma unroll
            for (int jt = 0; jt < 4; ++jt) {
                int col = col0 + wn * 64 + jt * 16 + c2;
                float bc = bias[col];
#pragma unroll
                for (int r = 0; r < 4; ++r) {
                    float v = acc[q * 2 + it][jt][r] + bc;
                    if (MODE == 2) v = v / (1.f + __expf(-v));
                    ((ushort_t*)Cout)[(size_t)(row + r) * N + col] = f2bf(v);
                }
            }
        }
}

// ---------------- MFMA attention: block = (b, h, q-tile of 64) ---------------
__global__ __launch_bounds__(256, 2) void attn_mfma_kernel(
    const ushort_t* __restrict__ qkv, const int* __restrict__ prio,
    const float* __restrict__ eb, const float* __restrict__ nm,
    ushort_t* __restrict__ out)
{
    int xb = blockIdx.x;
    int bid = (xb & 7) * 256 + (xb >> 3);
    int h = bid & 15, qt = (bid >> 4) & 3, b = bid >> 6;
    int t = threadIdx.x;

    __shared__ ushort_t Ks[256 * 72];    // 36864 B (reused as Ps[64*264])
    __shared__ ushort_t Vt[64 * 264];    // 33792 B  (transposed V: [d][key])

    int lane = t & 63, c = lane & 15, quad = lane >> 4;
    int w = t >> 6;
    int qbase = qt * 64 + w * 16 + quad * 4;

    int pr[16][4];
    const int* prp = prio + ((size_t)(b * N_ + qbase)) * N_ + c;
#pragma unroll
    for (int j = 0; j < 16; ++j)
#pragma unroll
        for (int r = 0; r < 4; ++r)
            pr[j][r] = prp[(size_t)r * N_ + j * 16];

    float nmq[4];
#pragma unroll
    for (int r = 0; r < 4; ++r) nmq[r] = nm[b * N_ + qbase + r];
    float nmk[16];
#pragma unroll
    for (int j = 0; j < 16; ++j) nmk[j] = nm[b * N_ + j * 16 + c];

    const ushort_t* qg = qkv + ((size_t)(b * N_ + qt * 64 + w * 16 + c)) * QS_ + h * HD_;
    short8 aq0 = *(const short8*)(const void*)(qg + quad * 8);
    short8 aq1 = *(const short8*)(const void*)(qg + 32 + quad * 8);

    int lr = t >> 3, lc = (t & 7) * 8;
    const ushort_t* kg = qkv + ((size_t)(b * N_)) * QS_ + 1024 + h * HD_;
#pragma unroll
    for (int r = 0; r < 256; r += 32)
        *(uint4*)&Ks[(lr + r) * 72 + lc] = *(const uint4*)&kg[(size_t)(lr + r) * QS_ + lc];
    const ushort_t* vg = qkv + ((size_t)(b * N_)) * QS_ + 2048 + h * HD_;
#pragma unroll
    for (int r = 0; r < 256; r += 32) {
        U16x8 uu; uu.u4 = *(const uint4*)&vg[(size_t)(lr + r) * QS_ + lc];
#pragma unroll
        for (int i = 0; i < 8; ++i)
            Vt[(lc + i) * 264 + lr + r] = uu.s[i];
    }

    const float* ebb = eb + (size_t)b * E_ * H_ + h;
    float badd[16][4];
#pragma unroll
    for (int j = 0; j < 16; ++j) {
        int key = j * 16 + c;
#pragma unroll
        for (int r = 0; r < 4; ++r) {
            int p = pr[j][r];
            float bias = 0.f;
            bool adj = (key == qbase + r);
            if (p >= 0) {
                int e = (p >= E_) ? p - E_ : p;
                bias = ebb[(size_t)e * H_];
                adj = true;
            }
            bool ok = adj && (nmq[r] != 0.f) && (nmk[j] != 0.f);
            badd[j][r] = ok ? bias : -3.0e38f;
        }
    }
    __syncthreads();

    f32x4 z = {0.f, 0.f, 0.f, 0.f};
    f32x4 acc[16];
#pragma unroll
    for (int j = 0; j < 16; ++j) acc[j] = z;
    __builtin_amdgcn_s_setprio(1);
#pragma unroll
    for (int j = 0; j < 16; ++j) {
        short8 b0 = *(const short8*)(const void*)(Ks + (j * 16 + c) * 72 + quad * 8);
        short8 b1 = *(const short8*)(const void*)(Ks + (j * 16 + c) * 72 + 32 + quad * 8);
        acc[j] = __builtin_amdgcn_mfma_f32_16x16x32_bf16(aq0, b0, acc[j], 0, 0, 0);
        acc[j] = __builtin_amdgcn_mfma_f32_16x16x32_bf16(aq1, b1, acc[j], 0, 0, 0);
    }
    __builtin_amdgcn_s_setprio(0);

#pragma unroll
    for (int j = 0; j < 16; ++j)
#pragma unroll
        for (int r = 0; r < 4; ++r)
            acc[j][r] = acc[j][r] * 0.125f + badd[j][r];

    float inv[4];
#pragma unroll
    for (int r = 0; r < 4; ++r) {
        float m = acc[0][r];
#pragma unroll
        for (int j = 1; j < 16; ++j) m = fmaxf(m, acc[j][r]);
        m = fmaxf(m, __shfl_xor(m, 1));
        m = fmaxf(m, __shfl_xor(m, 2));
        m = fmaxf(m, __shfl_xor(m, 4));
        m = fmaxf(m, __shfl_xor(m, 8));
        float s = 0.f;
#pragma unroll
        for (int j = 0; j < 16; ++j) {
            float p = __expf(acc[j][r] - m);
            acc[j][r] = p;
            s += p;
        }
        s += __shfl_xor(s, 1);
        s += __shfl_xor(s, 2);
        s += __shfl_xor(s, 4);
        s += __shfl_xor(s, 8);
        inv[r] = 1.f / s;
    }

    __syncthreads();
    ushort_t* Ps = Ks;
#pragma unroll
    for (int j = 0; j < 16; ++j)
#pragma unroll
        for (int r = 0; r < 4; ++r)
            Ps[(w * 16 + quad * 4 + r) * 264 + j * 16 + c] = f2bf(acc[j][r] * inv[r]);
    asm volatile("s_waitcnt lgkmcnt(0)" ::: "memory");

    f32x4 oc[4];
#pragma unroll
    for (int dt = 0; dt < 4; ++dt) oc[dt] = z;
    __builtin_amdgcn_s_setprio(1);
#pragma unroll
    for (int k0 = 0; k0 < 256; k0 += 32) {
        short8 ap = *(const short8*)(const void*)(Ps + (w * 16 + c) * 264 + k0 + quad * 8);
#pragma unroll
        for (int dt = 0; dt < 4; ++dt) {
            short8 bv = *(const short8*)(const void*)(Vt + (dt * 16 + c) * 264 + k0 + quad * 8);
            oc[dt] = __builtin_amdgcn_mfma_f32_16x16x32_bf16(ap, bv, oc[dt], 0, 0, 0);
        }
    }
    __builtin_amdgcn_s_setprio(0);
    ushort_t* og = out + ((size_t)(b * N_ + qt * 64 + w * 16)) * D_ + h * HD_;
#pragma unroll
    for (int dt = 0; dt < 4; ++dt)
#pragma unroll
        for (int r = 0; r < 4; ++r)
            og[(size_t)(quad * 4 + r) * D_ + dt * 16 + c] = f2bf(oc[dt][r]);
}

extern "C" void kernel_launch(void* const* d_in, const int* in_sizes, int n_in,
                              void* d_out, int out_size, void* d_ws, size_t ws_size,
                              hipStream_t stream) {
    const float* x     = (const float*)d_in[0];
    const float* nm    = (const float*)d_in[1];
    const int*   edges = (const int*)d_in[2];
    const float* emask = (const float*)d_in[3];
    const float* remb  = (const float*)d_in[4];
    const float* ln_g  = (const float*)d_in[5];
    const float* ln_b  = (const float*)d_in[6];
    const float* Wq = (const float*)d_in[7];  const float* bq = (const float*)d_in[8];
    const float* Wk = (const float*)d_in[9];  const float* bk = (const float*)d_in[10];
    const float* Wv = (const float*)d_in[11]; const float* bv = (const float*)d_in[12];
    const float* We = (const float*)d_in[13]; const float* be = (const float*)d_in[14];
    const float* Wo = (const float*)d_in[15]; const float* bo = (const float*)d_in[16];
    const float* ff_g = (const float*)d_in[17]; const float* ff_b = (const float*)d_in[18];
    const float* W1 = (const float*)d_in[19]; const float* b1 = (const float*)d_in[20];
    const float* W2 = (const float*)d_in[21]; const float* b2 = (const float*)d_in[22];
    float* out = (float*)d_out;

    char* ws = (char*)d_ws;
    const size_t MB = 1ll << 20;
    int*      prio = (int*)ws;                       // 0..8 MB
    float*    ebuf = (float*)(ws + 8 * MB);          // 8..9 MB
    ushort_t* xn   = (ushort_t*)(ws + 9 * MB);       // 9..25 MB (reused: attn_out)
    float*    x2   = (float*)(ws + 25 * MB);         // 25..57 MB
    ushort_t* hn   = (ushort_t*)(ws + 57 * MB);      // 57..73 MB
    ushort_t* qkv  = (ushort_t*)(ws + 73 * MB);      // 73..121 MB [8192][3072]
    ushort_t* mid  = qkv;                            // 73..137 MB (qkv dead by then)
    ushort_t* qkvT = (ushort_t*)(ws + 137 * MB);     // 137..143 MB [3072][1024]
    ushort_t* WoT  = (ushort_t*)(ws + 143 * MB);     // 143..145 MB
    ushort_t* W1T  = (ushort_t*)(ws + 145 * MB);     // 145..153 MB [4096][1024]
    ushort_t* W2T  = (ushort_t*)(ws + 153 * MB);     // 153..161 MB [1024][4096]
    float*    cb   = (float*)(ws + 161 * MB);        // 161..161.02 MB [3072]
    ushort_t* aout = xn;

    const int M = B_ * N_;   // 8192

    (void)hipMemsetAsync(prio, 0xFF, (size_t)B_ * N_ * N_ * sizeof(int), stream);
    eb_kernel<<<B_ * E_ / 16, 256, 0, stream>>>(remb, We, be, ebuf);
    scatter_kernel<<<(B_ * E_ + 255) / 256, 256, 0, stream>>>(edges, emask, prio);

    prep_kernel<<<12300, 256, 0, stream>>>(Wq, Wk, Wv, Wo, W1, W2, bq, bk, bv,
                                           qkvT, WoT, W1T, W2T, cb);

    ln_bf16_kernel<<<M, 256, 0, stream>>>(x, ln_g, ln_b, xn);

    // QKV projection: 256x256 8-phase, grid 32x12 = 384
    gemm256<0, 12><<<384, 512, 0, stream>>>(xn, qkvT, cb, qkv, M, QS_, D_);

    attn_mfma_kernel<<<B_ * H_ * 4, 256, 0, stream>>>(qkv, prio, ebuf, nm, aout);

    gemm_bf16<1><<<8 * 64, 256, 0, stream>>>(aout, WoT, bo, x, nullptr, x2, M, D_, D_);
    ln_bf16_kernel<<<M, 256, 0, stream>>>(x2, ff_g, ff_b, hn);

    // FFN up: 256x256 8-phase, grid 32x16 = 512
    gemm256<2, 16><<<512, 512, 0, stream>>>(hn, W1T, b1, mid, M, 4 * D_, D_);
    gemm_bf16<3><<<8 * 64, 256, 0, stream>>>(mid, W2T, b2, x2, nm, out, M, D_, 4 * D_);
}

// Round 6
// 502.654 us; speedup vs baseline: 1.0859x; 1.0671x over previous
//
#include <hip/hip_runtime.h>
#include <math.h>

#define B_  32
#define N_  256
#define D_  1024
#define H_  16
#define E_  512
#define ED_ 256
#define HD_ 64
#define QS_ 3072                  // merged qkv row stride
#define NEG_ (-3.4028234663852886e38f)

typedef __attribute__((ext_vector_type(8))) short short8;
typedef __attribute__((ext_vector_type(4))) float f32x4;
typedef __attribute__((ext_vector_type(16))) float f32x16;
typedef unsigned short ushort_t;
typedef unsigned int uint_t;

union U16x8 { uint4 u4; ushort_t s[8]; };

static __device__ __forceinline__ ushort_t f2bf(float f) {
    uint_t u = __builtin_bit_cast(uint_t, f);
    u = (u + 0x7fff + ((u >> 16) & 1)) >> 16;
    return (ushort_t)u;
}

// async global->LDS, 16 bytes per lane (m97 pattern)
static __device__ __forceinline__ void gload_lds16(const void* g, void* l) {
    __builtin_amdgcn_global_load_lds(
        (const __attribute__((address_space(1))) unsigned int*)g,
        (__attribute__((address_space(3))) unsigned int*)l, 16, 0, 0);
}

// ---------------- LayerNorm: fp32 in -> bf16 out -----------------------------
__global__ __launch_bounds__(256) void ln_bf16_kernel(const float* __restrict__ x,
                                                      const float* __restrict__ g,
                                                      const float* __restrict__ b,
                                                      ushort_t* __restrict__ out) {
    int row = blockIdx.x;
    const float* xr = x + (size_t)row * D_;
    ushort_t* yr = out + (size_t)row * D_;
    __shared__ float red[256];
    int t = threadIdx.x;
    float vals[4];
    float s = 0.f;
#pragma unroll
    for (int i = 0; i < 4; ++i) { vals[i] = xr[t + i * 256]; s += vals[i]; }
    red[t] = s; __syncthreads();
    for (int off = 128; off > 0; off >>= 1) { if (t < off) red[t] += red[t + off]; __syncthreads(); }
    float mean = red[0] * (1.f / D_);
    __syncthreads();
    float vs = 0.f;
#pragma unroll
    for (int i = 0; i < 4; ++i) { float d = vals[i] - mean; vs += d * d; }
    red[t] = vs; __syncthreads();
    for (int off = 128; off > 0; off >>= 1) { if (t < off) red[t] += red[t + off]; __syncthreads(); }
    float rstd = 1.f / sqrtf(red[0] * (1.f / D_) + 1e-5f);
#pragma unroll
    for (int i = 0; i < 4; ++i) {
        int c = t + i * 256;
        yr[c] = f2bf((vals[i] - mean) * rstd * g[c] + b[c]);
    }
}

// ---------------- fused prep: all weight transposes + concat bias ------------
__global__ __launch_bounds__(256) void prep_kernel(
    const float* __restrict__ Wq, const float* __restrict__ Wk,
    const float* __restrict__ Wv, const float* __restrict__ Wo,
    const float* __restrict__ W1, const float* __restrict__ W2,
    const float* __restrict__ bq, const float* __restrict__ bk,
    const float* __restrict__ bv,
    ushort_t* __restrict__ qkvT, ushort_t* __restrict__ WoT,
    ushort_t* __restrict__ W1T, ushort_t* __restrict__ W2T,
    float* __restrict__ cb)
{
    int id = blockIdx.x;
    if (id >= 12288) {
        int i = (id - 12288) * 256 + threadIdx.x;
        cb[i] = (i < 1024) ? bq[i] : ((i < 2048) ? bk[i - 1024] : bv[i - 2048]);
        return;
    }
    const float* in; ushort_t* outp; int K, N, tid;
    if (id < 4096) {
        int wsel = id >> 10; tid = id & 1023; K = D_; N = D_;
        in   = (wsel == 0) ? Wq : (wsel == 1) ? Wk : (wsel == 2) ? Wv : Wo;
        outp = (wsel == 0) ? qkvT : (wsel == 1) ? qkvT + 1024 * 1024
             : (wsel == 2) ? qkvT + 2 * 1024 * 1024 : WoT;
    } else if (id < 8192) { tid = id - 4096; K = D_; N = 4 * D_; in = W1; outp = W1T; }
    else                  { tid = id - 8192; K = 4 * D_; N = D_; in = W2; outp = W2T; }
    int tilesX = N >> 5;
    int n0 = (tid % tilesX) * 32, k0 = (tid / tilesX) * 32;

    __shared__ float tile[32][33];
    int tx = threadIdx.x & 31, ty = threadIdx.x >> 5;   // ty 0..7
#pragma unroll
    for (int r = 0; r < 4; ++r)
        tile[ty + r * 8][tx] = in[(size_t)(k0 + ty + r * 8) * N + n0 + tx];
    __syncthreads();
#pragma unroll
    for (int r = 0; r < 4; ++r)
        outp[(size_t)(n0 + ty + r * 8) * K + k0 + tx] = f2bf(tile[tx][ty + r * 8]);
}

// ---------------- edge-bias projection: eb[b,e,h] ----------------------------
__global__ __launch_bounds__(256) void eb_kernel(const float* __restrict__ re,
                                                 const float* __restrict__ We,
                                                 const float* __restrict__ be,
                                                 float* __restrict__ eb) {
    __shared__ float rs[16 * 256];
    __shared__ float wl[256 * 16];
    int t = threadIdx.x;
    int be0 = blockIdx.x * 16;     // base (b*E+e)
#pragma unroll
    for (int i = 0; i < 16; ++i) wl[t + i * 256] = We[t + i * 256];
#pragma unroll
    for (int i = 0; i < 16; ++i) rs[t + i * 256] = re[(size_t)be0 * 256 + t + i * 256];
    __syncthreads();
    int el = t >> 4, h = t & 15;
    float s = be[h];
#pragma unroll 8
    for (int i = 0; i < 256; ++i) s += rs[el * 256 + i] * wl[i * 16 + h];
    eb[(size_t)(be0 + el) * 16 + h] = s;
}

// ---------------- edge scatter: last-writer-wins priority table --------------
__global__ void scatter_kernel(const int* __restrict__ edges, const float* __restrict__ emask,
                               int* __restrict__ prio) {
    int idx = blockIdx.x * blockDim.x + threadIdx.x;   // b*E + e
    if (idx >= B_ * E_) return;
    if (emask[idx] == 0.f) return;
    int b = idx / E_, e = idx % E_;
    int s = edges[2 * idx], d = edges[2 * idx + 1];
    s = min(max(s, 0), N_ - 1);
    d = min(max(d, 0), N_ - 1);
    int* base = prio + (size_t)b * N_ * N_;
    atomicMax(&base[s * N_ + d], e);
    atomicMax(&base[d * N_ + s], e + E_);
}

// ---------------- bf16 MFMA GEMM (32x32x16): C = A[M,K] * BT[N,K]^T ---------
// 128x128 block, 4 waves in 2x2, each wave 64x64 = 2x2 tiles of 32x32.
// R6: 1-D grid + XCD-chunked supertile decode (T1).
// R9: BK=64 (was 32). Grid-capped shapes (modes 1,3: 512 blocks = 2 blocks/CU)
// pay one exposed-latency stage window per K-step; halving the step count
// halves the number of stall periods while the 32 KB LDS costs no occupancy
// anywhere (modes 0,2 are VGPR-capped at 4 blocks/CU = 128 KB budget).
// Swizzle upgraded to full row&7 key over the 8x16B row chunks (read conflicts
// 8-way -> 4-way vs the old (row>>1)&3 scheme).
// MODE 0: +bias -> bf16   1: +bias+res -> f32   2: silu(+bias) -> bf16
// MODE 3: +bias+res, *nm[row] -> f32
template<int MODE>
__global__ __launch_bounds__(256) void gemm_bf16(
    const ushort_t* __restrict__ A, const ushort_t* __restrict__ BT,
    const float* __restrict__ bias, const float* __restrict__ res,
    const float* __restrict__ nm, void* __restrict__ Cout,
    int M, int N, int K)
{
    __shared__ ushort_t As[128 * 64];   // 16 KB
    __shared__ ushort_t Bs[128 * 64];   // 16 KB
    int t = threadIdx.x;
    int lane = t & 63;
    int l31 = lane & 31, lh = lane >> 5;           // row/col in tile, k-half
    int w = t >> 6;
    int wr = (w >> 1) * 64, wc = (w & 1) * 64;

    // XCD-chunked supertile decode (bijective; hardware assigns bid -> XCD bid%8)
    int bid = blockIdx.x;
    int xcd = bid & 7;
    int lid = bid >> 3;            // sequential within this XCD's chunk
    int st  = lid >> 5;            // supertile = 8 rows x 4 cols = 32 blocks
    int ls  = lid & 31;
    int brow = xcd * 8 + (ls >> 2);
    int bcol = st * 4 + (ls & 3);
    int row0 = brow * 128, col0 = bcol * 128;

    const ushort_t* Ag = A + (size_t)row0 * K;
    const ushort_t* Bg = BT + (size_t)col0 * K;
    // staging: 4 calls/matrix, 32 rows each; thread t -> row t>>3, slot t&7.
    // LDS slot s of row r holds source chunk s ^ (r&7)  (16B chunks, 128B row)
    int srow = t >> 3;                             // 0..31
    int slot = t & 7;
    int sc = (slot ^ (srow & 7)) * 8;              // source chunk (elems)

    f32x16 acc[2][2];
#pragma unroll
    for (int i = 0; i < 2; ++i)
#pragma unroll
        for (int j = 0; j < 2; ++j)
#pragma unroll
            for (int r = 0; r < 16; ++r) acc[i][j][r] = 0.f;

    for (int k0 = 0; k0 < K; k0 += 64) {
#pragma unroll
        for (int i = 0; i < 4; ++i) {
            gload_lds16(Ag + (size_t)(i * 32 + srow) * K + k0 + sc, (char*)As + i * 4096 + t * 16);
            gload_lds16(Bg + (size_t)(i * 32 + srow) * K + k0 + sc, (char*)Bs + i * 4096 + t * 16);
        }
        __syncthreads();
#pragma unroll
        for (int ks = 0; ks < 4; ++ks) {
            short8 af[2], bf[2];
#pragma unroll
            for (int it = 0; it < 2; ++it) {
                int m = wr + it * 32 + l31;
                int x = ((ks * 2 + lh) ^ (m & 7)) * 16;     // byte offset in row
                af[it] = *(const short8*)((const char*)As + m * 128 + x);
            }
#pragma unroll
            for (int jt = 0; jt < 2; ++jt) {
                int n = wc + jt * 32 + l31;
                int x = ((ks * 2 + lh) ^ (n & 7)) * 16;
                bf[jt] = *(const short8*)((const char*)Bs + n * 128 + x);
            }
#pragma unroll
            for (int it = 0; it < 2; ++it)
#pragma unroll
                for (int jt = 0; jt < 2; ++jt)
                    acc[it][jt] = __builtin_amdgcn_mfma_f32_32x32x16_bf16(af[it], bf[jt], acc[it][jt], 0, 0, 0);
        }
        __syncthreads();
    }

    // C/D layout (m74/m101): col = lane&31, row = (reg&3) + 8*(reg>>2) + 4*(lane>>5)
#pragma unroll
    for (int it = 0; it < 2; ++it) {
#pragma unroll
        for (int jt = 0; jt < 2; ++jt) {
            int col = col0 + wc + jt * 32 + l31;
            float bcol_b = bias[col];
#pragma unroll
            for (int reg = 0; reg < 16; ++reg) {
                int row = row0 + wr + it * 32 + (reg & 3) + 8 * (reg >> 2) + 4 * lh;
                float v = acc[it][jt][reg] + bcol_b;
                if (MODE == 0) {
                    ((ushort_t*)Cout)[(size_t)row * N + col] = f2bf(v);
                } else if (MODE == 1) {
                    ((float*)Cout)[(size_t)row * N + col] = v + res[(size_t)row * N + col];
                } else if (MODE == 2) {
                    v = v / (1.f + __expf(-v));
                    ((ushort_t*)Cout)[(size_t)row * N + col] = f2bf(v);
                } else { // 3
                    v = (v + res[(size_t)row * N + col]) * nm[row];
                    ((float*)Cout)[(size_t)row * N + col] = v;
                }
            }
        }
    }
}

// ---------------- MFMA attention: block = (b, h, q-tile of 64) ---------------
__global__ __launch_bounds__(256, 2) void attn_mfma_kernel(
    const ushort_t* __restrict__ qkv, const int* __restrict__ prio,
    const float* __restrict__ eb, const float* __restrict__ nm,
    ushort_t* __restrict__ out)
{
    int xb = blockIdx.x;
    int bid = (xb & 7) * 256 + (xb >> 3);
    int h = bid & 15, qt = (bid >> 4) & 3, b = bid >> 6;
    int t = threadIdx.x;

    __shared__ ushort_t Ks[256 * 72];    // 36864 B (reused as Ps[64*264])
    __shared__ ushort_t Vt[64 * 264];    // 33792 B  (transposed V: [d][key])

    int lane = t & 63, c = lane & 15, quad = lane >> 4;
    int w = t >> 6;
    int qbase = qt * 64 + w * 16 + quad * 4;

    int pr[16][4];
    const int* prp = prio + ((size_t)(b * N_ + qbase)) * N_ + c;
#pragma unroll
    for (int j = 0; j < 16; ++j)
#pragma unroll
        for (int r = 0; r < 4; ++r)
            pr[j][r] = prp[(size_t)r * N_ + j * 16];

    float nmq[4];
#pragma unroll
    for (int r = 0; r < 4; ++r) nmq[r] = nm[b * N_ + qbase + r];
    float nmk[16];
#pragma unroll
    for (int j = 0; j < 16; ++j) nmk[j] = nm[b * N_ + j * 16 + c];

    const ushort_t* qg = qkv + ((size_t)(b * N_ + qt * 64 + w * 16 + c)) * QS_ + h * HD_;
    short8 aq0 = *(const short8*)(const void*)(qg + quad * 8);
    short8 aq1 = *(const short8*)(const void*)(qg + 32 + quad * 8);

    int lr = t >> 3, lc = (t & 7) * 8;
    const ushort_t* kg = qkv + ((size_t)(b * N_)) * QS_ + 1024 + h * HD_;
#pragma unroll
    for (int r = 0; r < 256; r += 32)
        *(uint4*)&Ks[(lr + r) * 72 + lc] = *(const uint4*)&kg[(size_t)(lr + r) * QS_ + lc];
    const ushort_t* vg = qkv + ((size_t)(b * N_)) * QS_ + 2048 + h * HD_;
#pragma unroll
    for (int r = 0; r < 256; r += 32) {
        U16x8 uu; uu.u4 = *(const uint4*)&vg[(size_t)(lr + r) * QS_ + lc];
#pragma unroll
        for (int i = 0; i < 8; ++i)
            Vt[(lc + i) * 264 + lr + r] = uu.s[i];
    }

    const float* ebb = eb + (size_t)b * E_ * H_ + h;
    float badd[16][4];
#pragma unroll
    for (int j = 0; j < 16; ++j) {
        int key = j * 16 + c;
#pragma unroll
        for (int r = 0; r < 4; ++r) {
            int p = pr[j][r];
            float bias = 0.f;
            bool adj = (key == qbase + r);
            if (p >= 0) {
                int e = (p >= E_) ? p - E_ : p;
                bias = ebb[(size_t)e * H_];
                adj = true;
            }
            bool ok = adj && (nmq[r] != 0.f) && (nmk[j] != 0.f);
            badd[j][r] = ok ? bias : -3.0e38f;
        }
    }
    __syncthreads();

    f32x4 z = {0.f, 0.f, 0.f, 0.f};
    f32x4 acc[16];
#pragma unroll
    for (int j = 0; j < 16; ++j) acc[j] = z;
    __builtin_amdgcn_s_setprio(1);
#pragma unroll
    for (int j = 0; j < 16; ++j) {
        short8 b0 = *(const short8*)(const void*)(Ks + (j * 16 + c) * 72 + quad * 8);
        short8 b1 = *(const short8*)(const void*)(Ks + (j * 16 + c) * 72 + 32 + quad * 8);
        acc[j] = __builtin_amdgcn_mfma_f32_16x16x32_bf16(aq0, b0, acc[j], 0, 0, 0);
        acc[j] = __builtin_amdgcn_mfma_f32_16x16x32_bf16(aq1, b1, acc[j], 0, 0, 0);
    }
    __builtin_amdgcn_s_setprio(0);

#pragma unroll
    for (int j = 0; j < 16; ++j)
#pragma unroll
        for (int r = 0; r < 4; ++r)
            acc[j][r] = acc[j][r] * 0.125f + badd[j][r];

    float inv[4];
#pragma unroll
    for (int r = 0; r < 4; ++r) {
        float m = acc[0][r];
#pragma unroll
        for (int j = 1; j < 16; ++j) m = fmaxf(m, acc[j][r]);
        m = fmaxf(m, __shfl_xor(m, 1));
        m = fmaxf(m, __shfl_xor(m, 2));
        m = fmaxf(m, __shfl_xor(m, 4));
        m = fmaxf(m, __shfl_xor(m, 8));
        float s = 0.f;
#pragma unroll
        for (int j = 0; j < 16; ++j) {
            float p = __expf(acc[j][r] - m);
            acc[j][r] = p;
            s += p;
        }
        s += __shfl_xor(s, 1);
        s += __shfl_xor(s, 2);
        s += __shfl_xor(s, 4);
        s += __shfl_xor(s, 8);
        inv[r] = 1.f / s;
    }

    __syncthreads();
    ushort_t* Ps = Ks;
#pragma unroll
    for (int j = 0; j < 16; ++j)
#pragma unroll
        for (int r = 0; r < 4; ++r)
            Ps[(w * 16 + quad * 4 + r) * 264 + j * 16 + c] = f2bf(acc[j][r] * inv[r]);
    asm volatile("s_waitcnt lgkmcnt(0)" ::: "memory");

    f32x4 oc[4];
#pragma unroll
    for (int dt = 0; dt < 4; ++dt) oc[dt] = z;
    __builtin_amdgcn_s_setprio(1);
#pragma unroll
    for (int k0 = 0; k0 < 256; k0 += 32) {
        short8 ap = *(const short8*)(const void*)(Ps + (w * 16 + c) * 264 + k0 + quad * 8);
#pragma unroll
        for (int dt = 0; dt < 4; ++dt) {
            short8 bv = *(const short8*)(const void*)(Vt + (dt * 16 + c) * 264 + k0 + quad * 8);
            oc[dt] = __builtin_amdgcn_mfma_f32_16x16x32_bf16(ap, bv, oc[dt], 0, 0, 0);
        }
    }
    __builtin_amdgcn_s_setprio(0);
    ushort_t* og = out + ((size_t)(b * N_ + qt * 64 + w * 16)) * D_ + h * HD_;
#pragma unroll
    for (int dt = 0; dt < 4; ++dt)
#pragma unroll
        for (int r = 0; r < 4; ++r)
            og[(size_t)(quad * 4 + r) * D_ + dt * 16 + c] = f2bf(oc[dt][r]);
}

extern "C" void kernel_launch(void* const* d_in, const int* in_sizes, int n_in,
                              void* d_out, int out_size, void* d_ws, size_t ws_size,
                              hipStream_t stream) {
    const float* x     = (const float*)d_in[0];
    const float* nm    = (const float*)d_in[1];
    const int*   edges = (const int*)d_in[2];
    const float* emask = (const float*)d_in[3];
    const float* remb  = (const float*)d_in[4];
    const float* ln_g  = (const float*)d_in[5];
    const float* ln_b  = (const float*)d_in[6];
    const float* Wq = (const float*)d_in[7];  const float* bq = (const float*)d_in[8];
    const float* Wk = (const float*)d_in[9];  const float* bk = (const float*)d_in[10];
    const float* Wv = (const float*)d_in[11]; const float* bv = (const float*)d_in[12];
    const float* We = (const float*)d_in[13]; const float* be = (const float*)d_in[14];
    const float* Wo = (const float*)d_in[15]; const float* bo = (const float*)d_in[16];
    const float* ff_g = (const float*)d_in[17]; const float* ff_b = (const float*)d_in[18];
    const float* W1 = (const float*)d_in[19]; const float* b1 = (const float*)d_in[20];
    const float* W2 = (const float*)d_in[21]; const float* b2 = (const float*)d_in[22];
    float* out = (float*)d_out;

    char* ws = (char*)d_ws;
    const size_t MB = 1ll << 20;
    int*      prio = (int*)ws;                       // 0..8 MB
    float*    ebuf = (float*)(ws + 8 * MB);          // 8..9 MB
    ushort_t* xn   = (ushort_t*)(ws + 9 * MB);       // 9..25 MB (reused: attn_out)
    float*    x2   = (float*)(ws + 25 * MB);         // 25..57 MB
    ushort_t* hn   = (ushort_t*)(ws + 57 * MB);      // 57..73 MB
    ushort_t* qkv  = (ushort_t*)(ws + 73 * MB);      // 73..121 MB [8192][3072]
    ushort_t* mid  = qkv;                            // 73..137 MB (qkv dead by then)
    ushort_t* qkvT = (ushort_t*)(ws + 137 * MB);     // 137..143 MB [3072][1024]
    ushort_t* WoT  = (ushort_t*)(ws + 143 * MB);     // 143..145 MB
    ushort_t* W1T  = (ushort_t*)(ws + 145 * MB);     // 145..153 MB [4096][1024]
    ushort_t* W2T  = (ushort_t*)(ws + 153 * MB);     // 153..161 MB [1024][4096]
    float*    cb   = (float*)(ws + 161 * MB);        // 161..161.02 MB [3072]
    ushort_t* aout = xn;

    const int M = B_ * N_;   // 8192

    (void)hipMemsetAsync(prio, 0xFF, (size_t)B_ * N_ * N_ * sizeof(int), stream);
    eb_kernel<<<B_ * E_ / 16, 256, 0, stream>>>(remb, We, be, ebuf);
    scatter_kernel<<<(B_ * E_ + 255) / 256, 256, 0, stream>>>(edges, emask, prio);

    prep_kernel<<<12300, 256, 0, stream>>>(Wq, Wk, Wv, Wo, W1, W2, bq, bk, bv,
                                           qkvT, WoT, W1T, W2T, cb);

    ln_bf16_kernel<<<M, 256, 0, stream>>>(x, ln_g, ln_b, xn);

    // 1-D grids: nbx*64 blocks (nbx = N/128)
    gemm_bf16<0><<<24 * 64, 256, 0, stream>>>(xn, qkvT, cb, nullptr, nullptr, qkv, M, QS_, D_);

    attn_mfma_kernel<<<B_ * H_ * 4, 256, 0, stream>>>(qkv, prio, ebuf, nm, aout);

    gemm_bf16<1><<<8 * 64, 256, 0, stream>>>(aout, WoT, bo, x, nullptr, x2, M, D_, D_);
    ln_bf16_kernel<<<M, 256, 0, stream>>>(x2, ff_g, ff_b, hn);

    gemm_bf16<2><<<32 * 64, 256, 0, stream>>>(hn, W1T, b1, nullptr, nullptr, mid, M, 4 * D_, D_);
    gemm_bf16<3><<<8 * 64, 256, 0, stream>>>(mid, W2T, b2, x2, nm, out, M, D_, 4 * D_);
}